// Round 8
// baseline (51.606 us; speedup 1.0000x reference)
//
#include <hip/hip_runtime.h>

#define AGENT_THRESH 0.5f
#define X_DIS_THRESH 1.5f
#define Y_DIS_THRESH 3.0f
#define DIS2_THRESH  9.0f
#define LOSS_WEIGHT  1.0f
#define FLT_BIG      3.402823466e+38f

constexpr int B = 128, A = 2048, M = 6, T = 12, C = 10;
constexpr int APB = 256;            // threads = agents per block
constexpr int CHUNKS = A / APB;     // 8
constexpr int NBLK = B * CHUNKS;    // 1024
constexpr int SLOTS = T * 2;        // 24
constexpr int GRP = 10;             // reducer threads per slot

// Fused kernel: R3's main body + last-block-done finalize.
// Coherence pattern proven in R5: plain stores -> __syncthreads ->
// __threadfence -> atomic ticket -> __threadfence -> volatile loads.
__global__ __launch_bounds__(APB) void pcl_fused_kernel(
    const float* __restrict__ ego,          // [B,T,2]
    const float* __restrict__ agent_preds,  // [B,A,2]
    const float* __restrict__ afp,          // [B,A,M,T,2]
    const float* __restrict__ scores,       // [B,A,C]
    const float* __restrict__ cls,          // [B,A,M]
    float* __restrict__ blockmins,          // [NBLK, 24]
    unsigned int* __restrict__ counter,     // modulo ticket (poison-immune)
    float* __restrict__ out)
{
    const int bid   = blockIdx.x;
    const int b     = bid / CHUNKS;
    const int chunk = bid % CHUNKS;
    const int tid   = threadIdx.x;
    const int a     = chunk * APB + tid;

    __shared__ float egoraw[SLOTS];
    __shared__ float predx[T], predy[T];
    __shared__ float sred[APB][25];
    __shared__ float spart[SLOTS * GRP];
    __shared__ float wsum[4];
    __shared__ int   slast;

    const size_t ba = (size_t)b * A + a;

    // --- issue all independent global loads up front ----------------------
    const float2* sp2 = (const float2*)(scores + ba * C);
    float2 s0 = sp2[0], s1 = sp2[1], s2 = sp2[2], s3 = sp2[3], s4 = sp2[4];
    const float2* cp2 = (const float2*)(cls + ba * M);
    float2 c0 = cp2[0], c1 = cp2[1], c2 = cp2[2];
    const float2 apxy = ((const float2*)agent_preds)[ba];

    if (tid < SLOTS) egoraw[tid] = ego[(size_t)b * SLOTS + tid];
    __syncthreads();
    if (tid < SLOTS) {                       // wave-parallel ego prefix
        const int coord = (tid >= T) ? 1 : 0;
        const int tt    = tid - T * coord;
        float s = 0.f;
        for (int i = 0; i <= tt; ++i) s += egoraw[2 * i + coord];
        if (coord) predy[tt] = s; else predx[tt] = s;
    }
    __syncthreads();

    // --- score argmax / validity ------------------------------------------
    float sv[C] = {s0.x, s0.y, s1.x, s1.y, s2.x, s2.y, s3.x, s3.y, s4.x, s4.y};
    float ms = sv[0];
    int   mi = 0;
    #pragma unroll
    for (int c = 1; c < C; ++c)
        if (sv[c] > ms) { ms = sv[c]; mi = c; }
    const bool valid = (ms >= AGENT_THRESH) && (mi <= 4);

    float p[SLOTS];
    #pragma unroll
    for (int k = 0; k < SLOTS; ++k) p[k] = FLT_BIG;

    if (valid) {
        float cv[M] = {c0.x, c0.y, c1.x, c1.y, c2.x, c2.y};
        float mc = cv[0];
        int   mm = 0;
        #pragma unroll
        for (int m = 1; m < M; ++m)
            if (cv[m] > mc) { mc = cv[m]; mm = m; }

        const float4* fp = (const float4*)(afp + (ba * M + mm) * (size_t)SLOTS);
        float4 f0 = fp[0], f1 = fp[1], f2 = fp[2], f3 = fp[3], f4 = fp[4], f5 = fp[5];
        float dxv[SLOTS];
        dxv[0]=f0.x; dxv[1]=f0.y; dxv[2]=f0.z; dxv[3]=f0.w;
        dxv[4]=f1.x; dxv[5]=f1.y; dxv[6]=f1.z; dxv[7]=f1.w;
        dxv[8]=f2.x; dxv[9]=f2.y; dxv[10]=f2.z; dxv[11]=f2.w;
        dxv[12]=f3.x; dxv[13]=f3.y; dxv[14]=f3.z; dxv[15]=f3.w;
        dxv[16]=f4.x; dxv[17]=f4.y; dxv[18]=f4.z; dxv[19]=f4.w;
        dxv[20]=f5.x; dxv[21]=f5.y; dxv[22]=f5.z; dxv[23]=f5.w;

        float csx = 0.f, csy = 0.f;
        #pragma unroll
        for (int t = 0; t < T; ++t) {
            csx += dxv[2 * t + 0];
            csy += dxv[2 * t + 1];
            const float dx = predx[t] - (apxy.x + csx);
            const float dy = predy[t] - (apxy.y + csy);
            const bool hit = (dx * dx + dy * dy <= DIS2_THRESH);
            p[2 * t + 0] = fminf(p[2 * t + 0], hit ? fabsf(dx) : FLT_BIG);
            p[2 * t + 1] = fminf(p[2 * t + 1], hit ? fabsf(dy) : FLT_BIG);
        }
    }

    // --- transpose-reduce --------------------------------------------------
    #pragma unroll
    for (int k = 0; k < SLOTS; ++k) sred[tid][k] = p[k];
    __syncthreads();

    if (tid < SLOTS * GRP) {
        const int s = tid % SLOTS;
        const int g = tid / SLOTS;
        float pm = FLT_BIG;
        for (int r = g; r < APB; r += GRP) pm = fminf(pm, sred[r][s]);
        spart[tid] = pm;
    }
    __syncthreads();

    if (tid < SLOTS) {
        float m = spart[tid];
        #pragma unroll
        for (int g = 1; g < GRP; ++g) m = fminf(m, spart[g * SLOTS + tid]);
        blockmins[(size_t)bid * SLOTS + tid] = m;   // plain store
    }
    __syncthreads();

    // --- last-block-done ticket (device fence both sides) ------------------
    if (tid == 0) {
        __threadfence();                            // release our 24 stores
        unsigned int prev = atomicAdd(counter, 1u);
        slast = ((prev % (unsigned)NBLK) == (unsigned)(NBLK - 1)) ? 1 : 0;
    }
    __syncthreads();

    if (slast) {
        __threadfence();                            // acquire others' stores
        volatile const float* vb = blockmins;
        float s = 0.f;
        for (int pi = tid; pi < B * SLOTS; pi += APB) {   // 12 pairs/thread
            const int bb = pi / SLOTS;
            const int sl = pi % SLOTS;
            float m = vb[((size_t)bb * CHUNKS + 0) * SLOTS + sl];
            #pragma unroll
            for (int c2 = 1; c2 < CHUNKS; ++c2)
                m = fminf(m, vb[((size_t)bb * CHUNKS + c2) * SLOTS + sl]);
            const float thr = (sl & 1) ? Y_DIS_THRESH : X_DIS_THRESH;
            s += (m > thr) ? 0.f : (thr - m);
        }
        #pragma unroll
        for (int off = 32; off > 0; off >>= 1) s += __shfl_down(s, off, 64);
        if ((tid & 63) == 0) wsum[tid >> 6] = s;
        __syncthreads();                            // uniform branch: legal
        if (tid == 0) {
            float tot = wsum[0] + wsum[1] + wsum[2] + wsum[3];
            out[0] = LOSS_WEIGHT * tot / (float)(B * SLOTS);
        }
    }
}

extern "C" void kernel_launch(void* const* d_in, const int* in_sizes, int n_in,
                              void* d_out, int out_size, void* d_ws, size_t ws_size,
                              hipStream_t stream) {
    const float* ego         = (const float*)d_in[0];  // [B,T,2]
    const float* agent_preds = (const float*)d_in[1];  // [B,A,2]
    const float* afp         = (const float*)d_in[2];  // [B,A,M,T,2]
    const float* scores      = (const float*)d_in[3];  // [B,A,C]
    const float* cls         = (const float*)d_in[4];  // [B,A,M]
    float* out               = (float*)d_out;

    float* blockmins         = (float*)d_ws;                          // 96 KB
    unsigned int* counter    = (unsigned int*)d_ws + NBLK * SLOTS + 32;

    pcl_fused_kernel<<<NBLK, APB, 0, stream>>>(
        ego, agent_preds, afp, scores, cls, blockmins, counter, out);
}